// Round 1
// baseline (623.974 us; speedup 1.0000x reference)
//
#include <hip/hip_runtime.h>

// ---------------------------------------------------------------------------
// GraphTransformer on MI355X.
//   h0 = adj @ x            -> bf16 hi/lo split MFMA GEMM (3 products, ~fp32 acc)
//   tail (per-row)          -> fp32 VALU kernels with LDS-staged weights
// ---------------------------------------------------------------------------

typedef __bf16 bf16x8 __attribute__((ext_vector_type(8)));
typedef float  f32x16 __attribute__((ext_vector_type(16)));

#define GN 16384
#define GD 128
#define BM 256
#define BK 32
#define KSPLIT 8
#define KRANGE (GN / KSPLIT)   // 2048
#define NIT (KRANGE / BK)      // 64

__device__ __forceinline__ unsigned short f2bf(float f) {
    unsigned u = __float_as_uint(f);
    unsigned r = (u + 0x7FFFu + ((u >> 16) & 1u)) >> 16;
    return (unsigned short)r;
}
__device__ __forceinline__ float bf2f(unsigned short u) {
    return __uint_as_float(((unsigned)u) << 16);
}

// ---------------------------------------------------------------------------
// P1: x [16384][128] fp32 -> xT_hi/xT_lo bf16, transposed to [col][k],
// tiled by 32-k, pre-swizzled for the GEMM's LDS layout:
//   element (c,k): tile=k>>5, idx = tile*4096 + c*32 + ((g^((c>>1)&3))<<3) + (k&7),
//   g = (k>>3)&3
// ---------------------------------------------------------------------------
__global__ void prep_x(const float* __restrict__ x,
                       unsigned short* __restrict__ xh,
                       unsigned short* __restrict__ xl) {
    const int kt = blockIdx.x;   // 0..511
    const int c  = threadIdx.x;  // 0..127
    float v[32];
#pragma unroll
    for (int i = 0; i < 32; ++i)
        v[i] = x[((long)kt * 32 + i) * 128 + c];
    const int f = (c >> 1) & 3;
    unsigned short* oh = xh + (long)kt * 4096 + c * 32;
    unsigned short* ol = xl + (long)kt * 4096 + c * 32;
#pragma unroll
    for (int g = 0; g < 4; ++g) {
        uint4 ph, pl;
        unsigned hp[4], lp[4];
#pragma unroll
        for (int q = 0; q < 4; ++q) {
            float a = v[g * 8 + q * 2], b = v[g * 8 + q * 2 + 1];
            unsigned short ha = f2bf(a), hb = f2bf(b);
            float la = a - bf2f(ha), lb = b - bf2f(hb);
            hp[q] = (unsigned)ha | ((unsigned)hb << 16);
            lp[q] = (unsigned)f2bf(la) | ((unsigned)f2bf(lb) << 16);
        }
        ph.x = hp[0]; ph.y = hp[1]; ph.z = hp[2]; ph.w = hp[3];
        pl.x = lp[0]; pl.y = lp[1]; pl.z = lp[2]; pl.w = lp[3];
        const int gp = g ^ f;
        *(uint4*)&oh[gp * 8] = ph;
        *(uint4*)&ol[gp * 8] = pl;
    }
}

// ---------------------------------------------------------------------------
// G: cpart[ks][i][d] = adj[i, ks-range] @ x[ks-range, d]   (hi/lo split MFMA)
// grid 512 = 64 M-blocks x 8 k-splits, 256 threads (4 waves), BM=256, BK=32
// ---------------------------------------------------------------------------
__global__ __launch_bounds__(256, 2) void gemm_adj(
    const float* __restrict__ adj,
    const unsigned short* __restrict__ xh,
    const unsigned short* __restrict__ xl,
    float* __restrict__ cpart) {
    __shared__ __align__(16) unsigned short Ah[BM * BK];
    __shared__ __align__(16) unsigned short Al[BM * BK];
    __shared__ __align__(16) unsigned short Bh[GD * BK];
    __shared__ __align__(16) unsigned short Bl[GD * BK];

    const int t    = threadIdx.x;
    const int bmi  = blockIdx.x & 63;
    const int ks   = blockIdx.x >> 6;
    const long rowbase = (long)bmi * BM;
    const int kb0  = ks * KRANGE;
    const int lane = t & 63, wid = t >> 6;
    const int arow = t >> 3;         // 0..31
    const int ak4  = (t & 7) * 4;    // 0,4,...,28

    f32x16 acc[2][4];
#pragma unroll
    for (int m = 0; m < 2; ++m)
#pragma unroll
        for (int n = 0; n < 4; ++n)
#pragma unroll
            for (int e = 0; e < 16; ++e) acc[m][n][e] = 0.0f;

    // prefetch A tile for it=0
    float4 pref[8];
#pragma unroll
    for (int p = 0; p < 8; ++p)
        pref[p] = *(const float4*)&adj[(rowbase + p * 32 + arow) * 16384L + kb0 + ak4];

    for (int it = 0; it < NIT; ++it) {
        const int kb = kb0 + it * BK;
        __syncthreads();
        // stage B (pre-swizzled linear copy)
        {
            const unsigned short* srch = xh + ((long)(kb >> 5)) * (GD * BK);
            const unsigned short* srcl = xl + ((long)(kb >> 5)) * (GD * BK);
#pragma unroll
            for (int j = 0; j < 2; ++j) {
                const int idx = j * 2048 + t * 8;
                *(uint4*)&Bh[idx] = *(const uint4*)&srch[idx];
                *(uint4*)&Bl[idx] = *(const uint4*)&srcl[idx];
            }
        }
        // stage A from prefetch regs: fp32 -> bf16 hi/lo, swizzled
#pragma unroll
        for (int p = 0; p < 8; ++p) {
            const int r = p * 32 + arow;
            const float4 v = pref[p];
            unsigned short h0b = f2bf(v.x), h1b = f2bf(v.y), h2b = f2bf(v.z), h3b = f2bf(v.w);
            float l0 = v.x - bf2f(h0b), l1 = v.y - bf2f(h1b), l2 = v.z - bf2f(h2b), l3 = v.w - bf2f(h3b);
            const int gp = (ak4 >> 3) ^ ((r >> 1) & 3);
            const int idx = r * 32 + gp * 8 + (ak4 & 7);
            uint2 hp, lp;
            hp.x = (unsigned)h0b | ((unsigned)h1b << 16);
            hp.y = (unsigned)h2b | ((unsigned)h3b << 16);
            lp.x = (unsigned)f2bf(l0) | ((unsigned)f2bf(l1) << 16);
            lp.y = (unsigned)f2bf(l2) | ((unsigned)f2bf(l3) << 16);
            *(uint2*)&Ah[idx] = hp;
            *(uint2*)&Al[idx] = lp;
        }
        __syncthreads();
        // issue next A-tile loads before MFMA phase (latency hides under MFMA)
        if (it + 1 < NIT) {
#pragma unroll
            for (int p = 0; p < 8; ++p)
                pref[p] = *(const float4*)&adj[(rowbase + p * 32 + arow) * 16384L + kb + BK + ak4];
        }
        // MFMA phase
#pragma unroll
        for (int s = 0; s < 2; ++s) {
            bf16x8 am[2], al2[2], bn[4], bl2[4];
#pragma unroll
            for (int m = 0; m < 2; ++m) {
                const int r = wid * 64 + m * 32 + (lane & 31);
                const int gp = (2 * s + (lane >> 5)) ^ ((r >> 1) & 3);
                const int idx = r * 32 + gp * 8;
                am[m]  = *(const bf16x8*)&Ah[idx];
                al2[m] = *(const bf16x8*)&Al[idx];
            }
#pragma unroll
            for (int n = 0; n < 4; ++n) {
                const int c = n * 32 + (lane & 31);
                const int gp = (2 * s + (lane >> 5)) ^ ((c >> 1) & 3);
                const int idx = c * 32 + gp * 8;
                bn[n]  = *(const bf16x8*)&Bh[idx];
                bl2[n] = *(const bf16x8*)&Bl[idx];
            }
#pragma unroll
            for (int m = 0; m < 2; ++m)
#pragma unroll
                for (int n = 0; n < 4; ++n) {
                    acc[m][n] = __builtin_amdgcn_mfma_f32_32x32x16_bf16(am[m], bn[n], acc[m][n], 0, 0, 0);
                    acc[m][n] = __builtin_amdgcn_mfma_f32_32x32x16_bf16(am[m], bl2[n], acc[m][n], 0, 0, 0);
                    acc[m][n] = __builtin_amdgcn_mfma_f32_32x32x16_bf16(al2[m], bn[n], acc[m][n], 0, 0, 0);
                }
        }
    }
    // write partials. C/D layout: col=lane&31, row=(r&3)+8*(r>>2)+4*(lane>>5)
    float* cp = cpart + (long)ks * GN * GD;
#pragma unroll
    for (int m = 0; m < 2; ++m)
#pragma unroll
        for (int n = 0; n < 4; ++n) {
            const int c = n * 32 + (lane & 31);
#pragma unroll
            for (int r = 0; r < 16; ++r) {
                const int rl = wid * 64 + m * 32 + (r & 3) + 8 * (r >> 2) + 4 * (lane >> 5);
                cp[(rowbase + rl) * (long)GD + c] = acc[m][n][r];
            }
        }
}

// ---------------------------------------------------------------------------
// R: h0 = sum_ks cpart[ks]
// ---------------------------------------------------------------------------
__global__ void reduce_cpart(const float* __restrict__ cpart, float* __restrict__ h0) {
    const long i = (long)(blockIdx.x * 256 + threadIdx.x) * 4;
    float4 s = *(const float4*)&cpart[i];
#pragma unroll
    for (int ks = 1; ks < KSPLIT; ++ks) {
        const float4 v = *(const float4*)&cpart[(long)ks * 2097152L + i];
        s.x += v.x; s.y += v.y; s.z += v.z; s.w += v.w;
    }
    *(float4*)&h0[i] = s;
}

// ---------------------------------------------------------------------------
// K1a: q = h0@Wq, k = h0@Wk, scores = q*k/4, softmax over groups of 8 -> wbuf
// ---------------------------------------------------------------------------
__global__ __launch_bounds__(256) void qk_softmax(
    const float* __restrict__ h0, const float* __restrict__ Wq,
    const float* __restrict__ Wk, float* __restrict__ wbuf) {
    __shared__ float WT[2][128 * 132];
    __shared__ float rows[8][128];
    __shared__ float qk[2][8][128];
    __shared__ float sl[8][128];
    const int t = threadIdx.x;
    {
        const int d = t >> 1, o0 = (t & 1) * 64;
        for (int q = 0; q < 2; ++q) {
            const float* W = q ? Wk : Wq;
#pragma unroll 8
            for (int i = 0; i < 64; ++i)
                WT[q][(o0 + i) * 132 + d] = W[d * 128 + o0 + i];
        }
    }
    const int o = t & 127, which = t >> 7;
    const long r0 = (long)blockIdx.x * 32;
    const float* WTo = &WT[which][o * 132];
    for (int rg = 0; rg < 4; ++rg) {
        __syncthreads();
        {
            const int rr = t >> 5, c4 = (t & 31) * 4;
            *(float4*)&rows[rr][c4] = *(const float4*)&h0[(r0 + rg * 8 + rr) * 128 + c4];
        }
        __syncthreads();
        float acc[8];
#pragma unroll
        for (int r = 0; r < 8; ++r) acc[r] = 0.f;
#pragma unroll
        for (int dg = 0; dg < 32; ++dg) {
            const float4 w4 = *(const float4*)&WTo[dg * 4];
#pragma unroll
            for (int r = 0; r < 8; ++r) {
                const float4 h4 = *(const float4*)&rows[r][dg * 4];
                acc[r] += w4.x * h4.x + w4.y * h4.y + w4.z * h4.z + w4.w * h4.w;
            }
        }
#pragma unroll
        for (int r = 0; r < 8; ++r) qk[which][r][o] = acc[r];
        __syncthreads();
#pragma unroll
        for (int rr = 0; rr < 4; ++rr) {
            const int r = which * 4 + rr;
            sl[r][o] = qk[0][r][o] * qk[1][r][o] * 0.25f;
        }
        __syncthreads();
        const int g8 = (o >> 3) << 3;
#pragma unroll
        for (int rr = 0; rr < 4; ++rr) {
            const int r = which * 4 + rr;
            float m = sl[r][g8];
#pragma unroll
            for (int j = 1; j < 8; ++j) m = fmaxf(m, sl[r][g8 + j]);
            float sum = 0.f;
#pragma unroll
            for (int j = 0; j < 8; ++j) sum += __expf(sl[r][g8 + j] - m);
            wbuf[(r0 + rg * 8 + r) * 128 + o] = __expf(sl[r][o] - m) / sum;
        }
    }
}

// ---------------------------------------------------------------------------
// K1b: v = h0@Wv; attn = wbuf*v; h = attn@Wo + h0; LN1 -> tln
// ---------------------------------------------------------------------------
__global__ __launch_bounds__(256) void attn_ln1(
    const float* __restrict__ h0, const float* __restrict__ Wv,
    const float* __restrict__ Wo, const float* __restrict__ wbuf,
    const float* __restrict__ ln1s, float* __restrict__ tln) {
    __shared__ float WT[2][128 * 132];
    __shared__ float rows[8][128];
    __shared__ float wrows[8][128];
    __shared__ float attn[8][128];
    __shared__ float hl[8][128];
    const int t = threadIdx.x;
    {
        const int d = t >> 1, o0 = (t & 1) * 64;
        for (int q = 0; q < 2; ++q) {
            const float* W = q ? Wo : Wv;
#pragma unroll 8
            for (int i = 0; i < 64; ++i)
                WT[q][(o0 + i) * 132 + d] = W[d * 128 + o0 + i];
        }
    }
    const int o = t & 127, which = t >> 7;
    const long r0 = (long)blockIdx.x * 32;
    for (int rg = 0; rg < 4; ++rg) {
        __syncthreads();
        {
            const int rr = t >> 5, c4 = (t & 31) * 4;
            const long rb = (r0 + rg * 8 + rr) * 128 + c4;
            *(float4*)&rows[rr][c4]  = *(const float4*)&h0[rb];
            *(float4*)&wrows[rr][c4] = *(const float4*)&wbuf[rb];
        }
        __syncthreads();
        {   // v then attn (4 rows per thread)
            float acc[4] = {0.f, 0.f, 0.f, 0.f};
            const float* W0 = &WT[0][o * 132];
#pragma unroll
            for (int dg = 0; dg < 32; ++dg) {
                const float4 w4 = *(const float4*)&W0[dg * 4];
#pragma unroll
                for (int rr = 0; rr < 4; ++rr) {
                    const float4 h4 = *(const float4*)&rows[which * 4 + rr][dg * 4];
                    acc[rr] += w4.x * h4.x + w4.y * h4.y + w4.z * h4.z + w4.w * h4.w;
                }
            }
#pragma unroll
            for (int rr = 0; rr < 4; ++rr) {
                const int r = which * 4 + rr;
                attn[r][o] = wrows[r][o] * acc[rr];
            }
        }
        __syncthreads();
        {   // h = attn@Wo + h0
            float acc[4] = {0.f, 0.f, 0.f, 0.f};
            const float* W1p = &WT[1][o * 132];
#pragma unroll
            for (int dg = 0; dg < 32; ++dg) {
                const float4 w4 = *(const float4*)&W1p[dg * 4];
#pragma unroll
                for (int rr = 0; rr < 4; ++rr) {
                    const float4 h4 = *(const float4*)&attn[which * 4 + rr][dg * 4];
                    acc[rr] += w4.x * h4.x + w4.y * h4.y + w4.z * h4.z + w4.w * h4.w;
                }
            }
#pragma unroll
            for (int rr = 0; rr < 4; ++rr) {
                const int r = which * 4 + rr;
                hl[r][o] = acc[rr] + rows[r][o];
            }
        }
        __syncthreads();
        {   // LayerNorm
            const int r = t >> 5, j = t & 31;
            const float4 a = *(const float4*)&hl[r][j * 4];
            float s1 = a.x + a.y + a.z + a.w;
            float s2 = a.x * a.x + a.y * a.y + a.z * a.z + a.w * a.w;
#pragma unroll
            for (int m = 1; m < 32; m <<= 1) {
                s1 += __shfl_xor(s1, m, 64);
                s2 += __shfl_xor(s2, m, 64);
            }
            const float mean = s1 * (1.f / 128.f);
            const float var  = s2 * (1.f / 128.f) - mean * mean;
            const float rstd = rsqrtf(var + 1e-6f);
            const float4 sc = *(const float4*)&ln1s[j * 4];
            float4 r4;
            r4.x = (a.x - mean) * rstd * sc.x;
            r4.y = (a.y - mean) * rstd * sc.y;
            r4.z = (a.z - mean) * rstd * sc.z;
            r4.w = (a.w - mean) * rstd * sc.w;
            *(float4*)&tln[(r0 + rg * 8 + r) * 128 + j * 4] = r4;
        }
    }
}

// ---------------------------------------------------------------------------
// K2a: fbuf = relu(tln @ W1)   [N,256]
// ---------------------------------------------------------------------------
__global__ __launch_bounds__(256) void ffn1(
    const float* __restrict__ tln, const float* __restrict__ W1,
    float* __restrict__ fbuf) {
    __shared__ float WT[256 * 132];
    __shared__ float rows[8][128];
    const int t = threadIdx.x;
    {
        const int d = t >> 1, o0 = (t & 1) * 128;
#pragma unroll 8
        for (int i = 0; i < 128; ++i)
            WT[(o0 + i) * 132 + d] = W1[d * 256 + o0 + i];
    }
    const long r0 = (long)blockIdx.x * 32;
    const float* WTo = &WT[t * 132];
    for (int rg = 0; rg < 4; ++rg) {
        __syncthreads();
        {
            const int rr = t >> 5, c4 = (t & 31) * 4;
            *(float4*)&rows[rr][c4] = *(const float4*)&tln[(r0 + rg * 8 + rr) * 128 + c4];
        }
        __syncthreads();
        float acc[8];
#pragma unroll
        for (int r = 0; r < 8; ++r) acc[r] = 0.f;
#pragma unroll
        for (int dg = 0; dg < 32; ++dg) {
            const float4 w4 = *(const float4*)&WTo[dg * 4];
#pragma unroll
            for (int r = 0; r < 8; ++r) {
                const float4 h4 = *(const float4*)&rows[r][dg * 4];
                acc[r] += w4.x * h4.x + w4.y * h4.y + w4.z * h4.z + w4.w * h4.w;
            }
        }
#pragma unroll
        for (int r = 0; r < 8; ++r)
            fbuf[(r0 + rg * 8 + r) * 256 + t] = fmaxf(acc[r], 0.f);
    }
}

// ---------------------------------------------------------------------------
// K2b1: g = fbuf @ W2; u = g + tln; LN2 -> uln
// ---------------------------------------------------------------------------
__global__ __launch_bounds__(256) void ffn2_ln2(
    const float* __restrict__ fbuf, const float* __restrict__ tln,
    const float* __restrict__ W2, const float* __restrict__ ln2s,
    float* __restrict__ uln) {
    __shared__ float WT[128 * 260];
    __shared__ float frows[8][256];
    __shared__ float trows[8][128];
    __shared__ float hl[8][128];
    const int t = threadIdx.x;
    {   // d = t (0..255)
#pragma unroll 8
        for (int o2 = 0; o2 < 128; ++o2)
            WT[o2 * 260 + t] = W2[t * 128 + o2];
    }
    const int o = t & 127, which = t >> 7;
    const long r0 = (long)blockIdx.x * 32;
    for (int rg = 0; rg < 4; ++rg) {
        __syncthreads();
        {
            const int rr = t >> 5, c8 = (t & 31) * 8;
            const long fb = (r0 + rg * 8 + rr) * 256 + c8;
            *(float4*)&frows[rr][c8]     = *(const float4*)&fbuf[fb];
            *(float4*)&frows[rr][c8 + 4] = *(const float4*)&fbuf[fb + 4];
            const int c4 = (t & 31) * 4;
            *(float4*)&trows[rr][c4] = *(const float4*)&tln[(r0 + rg * 8 + rr) * 128 + c4];
        }
        __syncthreads();
        float acc[4] = {0.f, 0.f, 0.f, 0.f};
        const float* WTo = &WT[o * 260];
#pragma unroll
        for (int dg = 0; dg < 64; ++dg) {
            const float4 w4 = *(const float4*)&WTo[dg * 4];
#pragma unroll
            for (int rr = 0; rr < 4; ++rr) {
                const float4 h4 = *(const float4*)&frows[which * 4 + rr][dg * 4];
                acc[rr] += w4.x * h4.x + w4.y * h4.y + w4.z * h4.z + w4.w * h4.w;
            }
        }
#pragma unroll
        for (int rr = 0; rr < 4; ++rr) {
            const int r = which * 4 + rr;
            hl[r][o] = acc[rr] + trows[r][o];
        }
        __syncthreads();
        {   // LN2
            const int r = t >> 5, j = t & 31;
            const float4 a = *(const float4*)&hl[r][j * 4];
            float s1 = a.x + a.y + a.z + a.w;
            float s2 = a.x * a.x + a.y * a.y + a.z * a.z + a.w * a.w;
#pragma unroll
            for (int m = 1; m < 32; m <<= 1) {
                s1 += __shfl_xor(s1, m, 64);
                s2 += __shfl_xor(s2, m, 64);
            }
            const float mean = s1 * (1.f / 128.f);
            const float var  = s2 * (1.f / 128.f) - mean * mean;
            const float rstd = rsqrtf(var + 1e-6f);
            const float4 sc = *(const float4*)&ln2s[j * 4];
            float4 r4;
            r4.x = (a.x - mean) * rstd * sc.x;
            r4.y = (a.y - mean) * rstd * sc.y;
            r4.z = (a.z - mean) * rstd * sc.z;
            r4.w = (a.w - mean) * rstd * sc.w;
            *(float4*)&uln[(r0 + rg * 8 + r) * 128 + j * 4] = r4;
        }
    }
}

// ---------------------------------------------------------------------------
// K2b2: out = uln @ Wout  [N,40]
// ---------------------------------------------------------------------------
__global__ __launch_bounds__(256) void outproj(
    const float* __restrict__ uln, const float* __restrict__ Wout,
    float* __restrict__ out) {
    __shared__ float WT[40 * 132];
    __shared__ float rows[32][128];
    const int t = threadIdx.x;
    if (t < 128) {
#pragma unroll 8
        for (int o2 = 0; o2 < 40; ++o2)
            WT[o2 * 132 + t] = Wout[t * 40 + o2];
    }
    const long r0 = (long)blockIdx.x * 32;
    {
#pragma unroll
        for (int q = 0; q < 4; ++q) {
            const int rr = t >> 3, cc = (t & 7) * 16 + q * 4;
            *(float4*)&rows[rr][cc] = *(const float4*)&uln[(r0 + rr) * 128 + cc];
        }
    }
    __syncthreads();
    const int o = t & 63, rg = t >> 6;
    if (o < 40) {
        float acc[8];
#pragma unroll
        for (int r = 0; r < 8; ++r) acc[r] = 0.f;
        const float* WTo = &WT[o * 132];
#pragma unroll
        for (int dg = 0; dg < 32; ++dg) {
            const float4 w4 = *(const float4*)&WTo[dg * 4];
#pragma unroll
            for (int r = 0; r < 8; ++r) {
                const float4 h4 = *(const float4*)&rows[rg * 8 + r][dg * 4];
                acc[r] += w4.x * h4.x + w4.y * h4.y + w4.z * h4.z + w4.w * h4.w;
            }
        }
#pragma unroll
        for (int r = 0; r < 8; ++r)
            out[(r0 + rg * 8 + r) * 40 + o] = acc[r];
    }
}

// ---------------------------------------------------------------------------
extern "C" void kernel_launch(void* const* d_in, const int* in_sizes, int n_in,
                              void* d_out, int out_size, void* d_ws, size_t ws_size,
                              hipStream_t stream) {
    const float* x    = (const float*)d_in[0];
    const float* adj  = (const float*)d_in[1];
    const float* Wq   = (const float*)d_in[2];
    const float* Wk   = (const float*)d_in[3];
    const float* Wv   = (const float*)d_in[4];
    const float* Wo   = (const float*)d_in[5];
    const float* ln1s = (const float*)d_in[6];
    const float* W1   = (const float*)d_in[7];
    const float* W2   = (const float*)d_in[8];
    const float* ln2s = (const float*)d_in[9];
    const float* Wout = (const float*)d_in[10];

    char* ws = (char*)d_ws;
    unsigned short* xh    = (unsigned short*)(ws);                       // 4 MB
    unsigned short* xl    = (unsigned short*)(ws + (4L << 20));          // 4 MB
    float* cpart          = (float*)(ws + (8L << 20));                   // 64 MB
    float* h0             = (float*)(ws + (72L << 20));                  // 8 MB (ends 80MB)
    // tail buffers alias the (dead-after-reduce) cpart region:
    float* wbuf = (float*)(ws + (8L << 20));    // 8 MB
    float* tln  = (float*)(ws + (16L << 20));   // 8 MB
    float* fbuf = (float*)(ws + (24L << 20));   // 16 MB
    float* uln  = (float*)(ws + (40L << 20));   // 8 MB

    prep_x<<<512, 128, 0, stream>>>(x, xh, xl);
    gemm_adj<<<512, 256, 0, stream>>>(adj, xh, xl, cpart);
    reduce_cpart<<<2048, 256, 0, stream>>>(cpart, h0);
    qk_softmax<<<512, 256, 0, stream>>>(h0, Wq, Wk, wbuf);
    attn_ln1<<<512, 256, 0, stream>>>(h0, Wv, Wo, wbuf, ln1s, tln);
    ffn1<<<512, 256, 0, stream>>>(tln, W1, fbuf);
    ffn2_ln2<<<512, 256, 0, stream>>>(fbuf, tln, W2, ln2s, uln);
    outproj<<<512, 256, 0, stream>>>(uln, Wout, (float*)d_out);
}

// Round 3
// 522.940 us; speedup vs baseline: 1.1932x; 1.1932x over previous
//
#include <hip/hip_runtime.h>

// ---------------------------------------------------------------------------
// GraphTransformer on MI355X, v2b (compile fix: native vector type for
// __builtin_nontemporal_load/store).
//   P1: x -> pre-swizzled bf16 hi/lo (xh/xl), 8 MB
//   G : cpart[ks] = adj @ x (bf16 hi/lo 3-product MFMA), NT adj loads,
//       global_load_lds B staging, XCD-pinned k-splits, KSPLIT=4, BM=128
//   T : fused tail (reduce + qkv attn + LN1 + FFN + LN2 + out), fp32 VALU
// ---------------------------------------------------------------------------

typedef __bf16 bf16x8 __attribute__((ext_vector_type(8)));
typedef float  f32x16 __attribute__((ext_vector_type(16)));
typedef float  f32x4  __attribute__((ext_vector_type(4)));

#define GN 16384
#define GD 128
#define BM 128
#define BK 32
#define KSPLIT 4
#define KRANGE (GN / KSPLIT)   // 4096
#define NIT (KRANGE / BK)      // 128

__device__ __forceinline__ unsigned short f2bf(float f) {
    unsigned u = __float_as_uint(f);
    unsigned r = (u + 0x7FFFu + ((u >> 16) & 1u)) >> 16;
    return (unsigned short)r;
}
__device__ __forceinline__ float bf2f(unsigned short u) {
    return __uint_as_float(((unsigned)u) << 16);
}

typedef __attribute__((address_space(1))) const void glb_cv;
typedef __attribute__((address_space(3))) void lds_v;
__device__ __forceinline__ void gload_lds16(const void* g, void* l) {
    __builtin_amdgcn_global_load_lds((glb_cv*)g, (lds_v*)l, 16, 0, 0);
}

// ---------------------------------------------------------------------------
// P1: x [16384][128] fp32 -> xh/xl bf16, transposed to [col][k] per 32-k tile,
// pre-swizzled: idx = tile*4096 + c*32 + ((g^((c>>1)&3))<<3) + (k&7), g=(k>>3)&3
// ---------------------------------------------------------------------------
__global__ void prep_x(const float* __restrict__ x,
                       unsigned short* __restrict__ xh,
                       unsigned short* __restrict__ xl) {
    const int kt = blockIdx.x;   // 0..511
    const int c  = threadIdx.x;  // 0..127
    float v[32];
#pragma unroll
    for (int i = 0; i < 32; ++i)
        v[i] = x[((long)kt * 32 + i) * 128 + c];
    const int f = (c >> 1) & 3;
    unsigned short* oh = xh + (long)kt * 4096 + c * 32;
    unsigned short* ol = xl + (long)kt * 4096 + c * 32;
#pragma unroll
    for (int g = 0; g < 4; ++g) {
        uint4 ph, pl;
        unsigned hp[4], lp[4];
#pragma unroll
        for (int q = 0; q < 4; ++q) {
            float a = v[g * 8 + q * 2], b = v[g * 8 + q * 2 + 1];
            unsigned short ha = f2bf(a), hb = f2bf(b);
            float la = a - bf2f(ha), lb = b - bf2f(hb);
            hp[q] = (unsigned)ha | ((unsigned)hb << 16);
            lp[q] = (unsigned)f2bf(la) | ((unsigned)f2bf(lb) << 16);
        }
        ph.x = hp[0]; ph.y = hp[1]; ph.z = hp[2]; ph.w = hp[3];
        pl.x = lp[0]; pl.y = lp[1]; pl.z = lp[2]; pl.w = lp[3];
        const int gp = g ^ f;
        *(uint4*)&oh[gp * 8] = ph;
        *(uint4*)&ol[gp * 8] = pl;
    }
}

// ---------------------------------------------------------------------------
// G: cpart[ks][i][d] = adj[i, ks-range] @ x[ks-range, d]
// grid 512: xcd=b&7 -> ks=xcd>>1 (B slice L2-pinned per XCD pair),
// bmi=(b>>3)|((xcd&1)<<6). 256 thr (4 waves), each wave: 32 rows x 128 cols.
// ---------------------------------------------------------------------------
__global__ __launch_bounds__(256, 2) void gemm_adj(
    const float* __restrict__ adj,
    const unsigned short* __restrict__ xh,
    const unsigned short* __restrict__ xl,
    float* __restrict__ cpart) {
    __shared__ __align__(16) unsigned short Ah[BM * BK];
    __shared__ __align__(16) unsigned short Al[BM * BK];
    __shared__ __align__(16) unsigned short Bh[GD * BK];
    __shared__ __align__(16) unsigned short Bl[GD * BK];

    const int t   = threadIdx.x;
    const int b   = blockIdx.x;
    const int xcd = b & 7;
    const int ks  = xcd >> 1;
    const int bmi = (b >> 3) | ((xcd & 1) << 6);
    const long rowbase = (long)bmi * BM;
    const int kb0 = ks * KRANGE;
    const int lane = t & 63, wid = t >> 6;
    const int ra = t >> 1;           // A row 0..127 (2 threads/row)
    const int ca = (t & 1) * 16;     // col offset 0 or 16

    f32x16 acc[4];
#pragma unroll
    for (int n = 0; n < 4; ++n)
#pragma unroll
        for (int e = 0; e < 16; ++e) acc[n][e] = 0.0f;

    const float* abase = adj + (rowbase + ra) * 16384L + ca;
    f32x4 pref[4];
#pragma unroll
    for (int p = 0; p < 4; ++p)
        pref[p] = __builtin_nontemporal_load((const f32x4*)(abase + kb0 + p * 4));

    const int rsw = (ra >> 1) & 3;
    const int rm  = wid * 32 + (lane & 31);   // MFMA row
    const int rswm = (rm >> 1) & 3;

    for (int it = 0; it < NIT; ++it) {
        const int kb = kb0 + it * BK;
        __syncthreads();
        // B stage: async global->LDS (pre-swizzled, linear)
        {
            const char* sh = (const char*)(xh + (long)(kb >> 5) * 4096);
            const char* sl = (const char*)(xl + (long)(kb >> 5) * 4096);
#pragma unroll
            for (int j = 0; j < 2; ++j) {
                const int seg = wid + j * 4;
                gload_lds16(sh + seg * 1024 + lane * 16, ((char*)Bh) + seg * 1024);
                gload_lds16(sl + seg * 1024 + lane * 16, ((char*)Bl) + seg * 1024);
            }
        }
        // A stage: fp32 -> bf16 hi/lo (rounded), swizzled
#pragma unroll
        for (int g = 0; g < 2; ++g) {
            const f32x4 va = pref[g * 2], vb = pref[g * 2 + 1];
            float f[8] = {va[0], va[1], va[2], va[3], vb[0], vb[1], vb[2], vb[3]};
            unsigned hu[4], lu[4];
#pragma unroll
            for (int q = 0; q < 4; ++q) {
                unsigned short ha = f2bf(f[2 * q]), hb = f2bf(f[2 * q + 1]);
                float la = f[2 * q] - bf2f(ha), lb = f[2 * q + 1] - bf2f(hb);
                hu[q] = (unsigned)ha | ((unsigned)hb << 16);
                lu[q] = (unsigned)f2bf(la) | ((unsigned)f2bf(lb) << 16);
            }
            const int gp = ((ca >> 3) + g) ^ rsw;
            uint4 H4, L4;
            H4.x = hu[0]; H4.y = hu[1]; H4.z = hu[2]; H4.w = hu[3];
            L4.x = lu[0]; L4.y = lu[1]; L4.z = lu[2]; L4.w = lu[3];
            *(uint4*)&Ah[ra * 32 + gp * 8] = H4;
            *(uint4*)&Al[ra * 32 + gp * 8] = L4;
        }
        __syncthreads();   // drains B-loads into LDS + A ds_writes
        // prefetch next A tile AFTER the barrier: stays in flight over MFMA
        if (it + 1 < NIT) {
#pragma unroll
            for (int p = 0; p < 4; ++p)
                pref[p] = __builtin_nontemporal_load(
                    (const f32x4*)(abase + kb + BK + p * 4));
        }
        // MFMA phase
#pragma unroll
        for (int s = 0; s < 2; ++s) {
            const int hh = 2 * s + (lane >> 5);
            bf16x8 am, al2, bn[4], bl4[4];
            am  = *(const bf16x8*)&Ah[rm * 32 + (hh ^ rswm) * 8];
            al2 = *(const bf16x8*)&Al[rm * 32 + (hh ^ rswm) * 8];
#pragma unroll
            for (int n = 0; n < 4; ++n) {
                const int c = n * 32 + (lane & 31);
                const int gp = hh ^ ((c >> 1) & 3);
                bn[n]  = *(const bf16x8*)&Bh[c * 32 + gp * 8];
                bl4[n] = *(const bf16x8*)&Bl[c * 32 + gp * 8];
            }
#pragma unroll
            for (int n = 0; n < 4; ++n) {
                acc[n] = __builtin_amdgcn_mfma_f32_32x32x16_bf16(am, bn[n], acc[n], 0, 0, 0);
                acc[n] = __builtin_amdgcn_mfma_f32_32x32x16_bf16(am, bl4[n], acc[n], 0, 0, 0);
                acc[n] = __builtin_amdgcn_mfma_f32_32x32x16_bf16(al2, bn[n], acc[n], 0, 0, 0);
            }
        }
    }
    // epilogue: C/D layout row=(e&3)+8*(e>>2)+4*(lane>>5), col=lane&31
    float* cp = cpart + (long)ks * GN * GD;
#pragma unroll
    for (int n = 0; n < 4; ++n) {
        const int c = n * 32 + (lane & 31);
#pragma unroll
        for (int e = 0; e < 16; ++e) {
            const int rl = wid * 32 + (e & 3) + 8 * (e >> 2) + 4 * (lane >> 5);
            __builtin_nontemporal_store(acc[n][e], &cp[(rowbase + rl) * (long)GD + c]);
        }
    }
}

// ---------------------------------------------------------------------------
// T: fused tail. 512 blocks x 256 thr, 32 rows/block. Outer-product matmuls,
// row-major weights straight from L1/L2. LDS: H(16K)+C(16K)+FB(32K)=64K.
// Thread (ogrp=t&31 -> 4 outs, rowgrp=t>>5 -> 4 rows).
// ---------------------------------------------------------------------------
__global__ __launch_bounds__(256, 2) void tail_fused(
    const float* __restrict__ cpart,
    const float* __restrict__ Wq, const float* __restrict__ Wk,
    const float* __restrict__ Wv, const float* __restrict__ Wo,
    const float* __restrict__ ln1s,
    const float* __restrict__ W1, const float* __restrict__ W2,
    const float* __restrict__ ln2s, const float* __restrict__ Wout,
    float* __restrict__ out) {
    __shared__ __align__(16) float H[32][128];
    __shared__ __align__(16) float C[32][128];
    __shared__ __align__(16) float FB[32 * 256];
    float (*B1)[128] = (float (*)[128])FB;

    const int t = threadIdx.x;
    const int ogrp = t & 31, rowgrp = t >> 5;
    const int o4 = ogrp * 4, rbase = rowgrp * 4;
    const long r0 = (long)blockIdx.x * 32;

    // --- step 1: H = sum_ks cpart[ks] ---
#pragma unroll
    for (int j = 0; j < 4; ++j) {
        const int p = t + 256 * j;
        const int row = p >> 5, c4 = (p & 31) * 4;
        f32x4 s = __builtin_nontemporal_load(
            (const f32x4*)&cpart[(r0 + row) * 128 + c4]);
#pragma unroll
        for (int ks = 1; ks < KSPLIT; ++ks) {
            f32x4 v = __builtin_nontemporal_load(
                (const f32x4*)&cpart[((long)ks * GN + r0 + row) * 128 + c4]);
            s += v;
        }
        *(f32x4*)&H[row][c4] = s;
    }
    __syncthreads();

    // --- step 2: q,k ---
    float qa[4][4] = {}, ka[4][4] = {};
    for (int dg = 0; dg < 32; ++dg) {
        f32x4 h4[4];
#pragma unroll
        for (int rr = 0; rr < 4; ++rr) h4[rr] = *(const f32x4*)&H[rbase + rr][dg * 4];
#pragma unroll
        for (int i = 0; i < 4; ++i) {
            const int d = dg * 4 + i;
            const f32x4 wq = *(const f32x4*)&Wq[d * 128 + o4];
            const f32x4 wk = *(const f32x4*)&Wk[d * 128 + o4];
#pragma unroll
            for (int rr = 0; rr < 4; ++rr) {
                const float hv = h4[rr][i];
                qa[rr][0] += hv * wq[0]; qa[rr][1] += hv * wq[1];
                qa[rr][2] += hv * wq[2]; qa[rr][3] += hv * wq[3];
                ka[rr][0] += hv * wk[0]; ka[rr][1] += hv * wk[1];
                ka[rr][2] += hv * wk[2]; ka[rr][3] += hv * wk[3];
            }
        }
    }
    // --- softmax over 8-groups (partner lane = lane^1) ---
    float w[4][4];
#pragma unroll
    for (int rr = 0; rr < 4; ++rr) {
        float s0 = qa[rr][0] * ka[rr][0] * 0.25f;
        float s1 = qa[rr][1] * ka[rr][1] * 0.25f;
        float s2 = qa[rr][2] * ka[rr][2] * 0.25f;
        float s3 = qa[rr][3] * ka[rr][3] * 0.25f;
        float m = fmaxf(fmaxf(s0, s1), fmaxf(s2, s3));
        m = fmaxf(m, __shfl_xor(m, 1, 64));
        float e0 = __expf(s0 - m), e1 = __expf(s1 - m);
        float e2 = __expf(s2 - m), e3 = __expf(s3 - m);
        float sum = e0 + e1 + e2 + e3;
        sum += __shfl_xor(sum, 1, 64);
        float inv = 1.0f / sum;
        w[rr][0] = e0 * inv; w[rr][1] = e1 * inv;
        w[rr][2] = e2 * inv; w[rr][3] = e3 * inv;
    }
    // --- step 3: v, attn -> B1 ---
    {
        float va[4][4] = {};
        for (int dg = 0; dg < 32; ++dg) {
            f32x4 h4[4];
#pragma unroll
            for (int rr = 0; rr < 4; ++rr) h4[rr] = *(const f32x4*)&H[rbase + rr][dg * 4];
#pragma unroll
            for (int i = 0; i < 4; ++i) {
                const int d = dg * 4 + i;
                const f32x4 wv = *(const f32x4*)&Wv[d * 128 + o4];
#pragma unroll
                for (int rr = 0; rr < 4; ++rr) {
                    const float hv = h4[rr][i];
                    va[rr][0] += hv * wv[0]; va[rr][1] += hv * wv[1];
                    va[rr][2] += hv * wv[2]; va[rr][3] += hv * wv[3];
                }
            }
        }
#pragma unroll
        for (int rr = 0; rr < 4; ++rr) {
            f32x4 a;
            a[0] = w[rr][0] * va[rr][0]; a[1] = w[rr][1] * va[rr][1];
            a[2] = w[rr][2] * va[rr][2]; a[3] = w[rr][3] * va[rr][3];
            *(f32x4*)&B1[rbase + rr][o4] = a;
        }
    }
    __syncthreads();
    // --- step 4: Wo + residual + LN1 -> C ---
    {
        float oa[4][4] = {};
        for (int dg = 0; dg < 32; ++dg) {
            f32x4 h4[4];
#pragma unroll
            for (int rr = 0; rr < 4; ++rr) h4[rr] = *(const f32x4*)&B1[rbase + rr][dg * 4];
#pragma unroll
            for (int i = 0; i < 4; ++i) {
                const int d = dg * 4 + i;
                const f32x4 wo = *(const f32x4*)&Wo[d * 128 + o4];
#pragma unroll
                for (int rr = 0; rr < 4; ++rr) {
                    const float hv = h4[rr][i];
                    oa[rr][0] += hv * wo[0]; oa[rr][1] += hv * wo[1];
                    oa[rr][2] += hv * wo[2]; oa[rr][3] += hv * wo[3];
                }
            }
        }
        const f32x4 g1 = *(const f32x4*)&ln1s[o4];
#pragma unroll
        for (int rr = 0; rr < 4; ++rr) {
            const f32x4 hres = *(const f32x4*)&H[rbase + rr][o4];
            float u0 = oa[rr][0] + hres[0], u1 = oa[rr][1] + hres[1];
            float u2 = oa[rr][2] + hres[2], u3 = oa[rr][3] + hres[3];
            float s1 = u0 + u1 + u2 + u3;
            float s2 = u0 * u0 + u1 * u1 + u2 * u2 + u3 * u3;
#pragma unroll
            for (int mk = 1; mk < 32; mk <<= 1) {
                s1 += __shfl_xor(s1, mk, 64);
                s2 += __shfl_xor(s2, mk, 64);
            }
            const float mean = s1 * (1.f / 128.f);
            const float var  = s2 * (1.f / 128.f) - mean * mean;
            const float rstd = rsqrtf(var + 1e-6f);
            f32x4 cvr;
            cvr[0] = (u0 - mean) * rstd * g1[0]; cvr[1] = (u1 - mean) * rstd * g1[1];
            cvr[2] = (u2 - mean) * rstd * g1[2]; cvr[3] = (u3 - mean) * rstd * g1[3];
            *(f32x4*)&C[rbase + rr][o4] = cvr;
        }
    }
    __syncthreads();
    // --- step 5: FB = relu(C @ W1) [32][256] ---
#pragma unroll
    for (int h = 0; h < 2; ++h) {
        float fa[4][4] = {};
        for (int dg = 0; dg < 32; ++dg) {
            f32x4 h4[4];
#pragma unroll
            for (int rr = 0; rr < 4; ++rr) h4[rr] = *(const f32x4*)&C[rbase + rr][dg * 4];
#pragma unroll
            for (int i = 0; i < 4; ++i) {
                const int d = dg * 4 + i;
                const f32x4 w1 = *(const f32x4*)&W1[d * 256 + h * 128 + o4];
#pragma unroll
                for (int rr = 0; rr < 4; ++rr) {
                    const float hv = h4[rr][i];
                    fa[rr][0] += hv * w1[0]; fa[rr][1] += hv * w1[1];
                    fa[rr][2] += hv * w1[2]; fa[rr][3] += hv * w1[3];
                }
            }
        }
#pragma unroll
        for (int rr = 0; rr < 4; ++rr) {
            f32x4 a;
            a[0] = fmaxf(fa[rr][0], 0.f); a[1] = fmaxf(fa[rr][1], 0.f);
            a[2] = fmaxf(fa[rr][2], 0.f); a[3] = fmaxf(fa[rr][3], 0.f);
            *(f32x4*)&FB[(rbase + rr) * 256 + h * 128 + o4] = a;
        }
        __syncthreads();
    }
    // --- step 6: W2 + residual + LN2 -> C (in place) ---
    {
        float ga[4][4] = {};
        for (int dg = 0; dg < 64; ++dg) {
            f32x4 f4[4];
#pragma unroll
            for (int rr = 0; rr < 4; ++rr)
                f4[rr] = *(const f32x4*)&FB[(rbase + rr) * 256 + dg * 4];
#pragma unroll
            for (int i = 0; i < 4; ++i) {
                const int d = dg * 4 + i;
                const f32x4 w2 = *(const f32x4*)&W2[d * 128 + o4];
#pragma unroll
                for (int rr = 0; rr < 4; ++rr) {
                    const float hv = f4[rr][i];
                    ga[rr][0] += hv * w2[0]; ga[rr][1] += hv * w2[1];
                    ga[rr][2] += hv * w2[2]; ga[rr][3] += hv * w2[3];
                }
            }
        }
        const f32x4 g2 = *(const f32x4*)&ln2s[o4];
#pragma unroll
        for (int rr = 0; rr < 4; ++rr) {
            const f32x4 cres = *(const f32x4*)&C[rbase + rr][o4];
            float u0 = ga[rr][0] + cres[0], u1 = ga[rr][1] + cres[1];
            float u2 = ga[rr][2] + cres[2], u3 = ga[rr][3] + cres[3];
            float s1 = u0 + u1 + u2 + u3;
            float s2 = u0 * u0 + u1 * u1 + u2 * u2 + u3 * u3;
#pragma unroll
            for (int mk = 1; mk < 32; mk <<= 1) {
                s1 += __shfl_xor(s1, mk, 64);
                s2 += __shfl_xor(s2, mk, 64);
            }
            const float mean = s1 * (1.f / 128.f);
            const float var  = s2 * (1.f / 128.f) - mean * mean;
            const float rstd = rsqrtf(var + 1e-6f);
            f32x4 cvr;
            cvr[0] = (u0 - mean) * rstd * g2[0]; cvr[1] = (u1 - mean) * rstd * g2[1];
            cvr[2] = (u2 - mean) * rstd * g2[2]; cvr[3] = (u3 - mean) * rstd * g2[3];
            *(f32x4*)&C[rbase + rr][o4] = cvr;
        }
    }
    __syncthreads();
    // --- step 7: out = C @ Wout [32][40] ---
    {
        const int r7 = t >> 3, ob = t & 7;
        float acc[5] = {0.f, 0.f, 0.f, 0.f, 0.f};
        for (int dg = 0; dg < 32; ++dg) {
            const f32x4 c4 = *(const f32x4*)&C[r7][dg * 4];
#pragma unroll
            for (int i = 0; i < 4; ++i) {
                const int d = dg * 4 + i;
                const float hv = c4[i];
#pragma unroll
                for (int jj = 0; jj < 5; ++jj)
                    acc[jj] += hv * Wout[d * 40 + ob + 8 * jj];
            }
        }
#pragma unroll
        for (int jj = 0; jj < 5; ++jj)
            out[(r0 + r7) * 40 + ob + 8 * jj] = acc[jj];
    }
}

// ---------------------------------------------------------------------------
extern "C" void kernel_launch(void* const* d_in, const int* in_sizes, int n_in,
                              void* d_out, int out_size, void* d_ws, size_t ws_size,
                              hipStream_t stream) {
    const float* x    = (const float*)d_in[0];
    const float* adj  = (const float*)d_in[1];
    const float* Wq   = (const float*)d_in[2];
    const float* Wk   = (const float*)d_in[3];
    const float* Wv   = (const float*)d_in[4];
    const float* Wo   = (const float*)d_in[5];
    const float* ln1s = (const float*)d_in[6];
    const float* W1   = (const float*)d_in[7];
    const float* W2   = (const float*)d_in[8];
    const float* ln2s = (const float*)d_in[9];
    const float* Wout = (const float*)d_in[10];

    char* ws = (char*)d_ws;
    unsigned short* xh = (unsigned short*)(ws);                  // 4 MB
    unsigned short* xl = (unsigned short*)(ws + (4L << 20));     // 4 MB
    float* cpart       = (float*)(ws + (8L << 20));              // 32 MB

    prep_x<<<512, 128, 0, stream>>>(x, xh, xl);
    gemm_adj<<<512, 256, 0, stream>>>(adj, xh, xl, cpart);
    tail_fused<<<512, 256, 0, stream>>>(cpart, Wq, Wk, Wv, Wo, ln1s,
                                        W1, W2, ln2s, Wout, (float*)d_out);
}

// Round 4
// 485.020 us; speedup vs baseline: 1.2865x; 1.0782x over previous
//
#include <hip/hip_runtime.h>

// ---------------------------------------------------------------------------
// GraphTransformer on MI355X, v3.
//   P1: x -> pre-swizzled bf16 hi/lo (xh/xl), 8 MB
//   G : cpart[ks] = adj @ x, bf16 hi/lo 3-product MFMA.
//       KSPLIT=8 (1024 blocks, 3/CU), 2-iter A superchunks (256B/row visit),
//       NT adj loads, global_load_lds B staging, XCD-pinned k-slices.
//   T : fused tail (reduce + qkv attn + LN1 + FFN + LN2 + out), fp32 VALU
// ---------------------------------------------------------------------------

typedef __bf16 bf16x8 __attribute__((ext_vector_type(8)));
typedef float  f32x16 __attribute__((ext_vector_type(16)));
typedef float  f32x4  __attribute__((ext_vector_type(4)));

#define GN 16384
#define GD 128
#define BM 128
#define BK 32
#define KSPLIT 8
#define KRANGE (GN / KSPLIT)   // 2048
#define NIT (KRANGE / BK)      // 64
#define NSUP (NIT / 2)         // 32

__device__ __forceinline__ unsigned short f2bf(float f) {
    unsigned u = __float_as_uint(f);
    unsigned r = (u + 0x7FFFu + ((u >> 16) & 1u)) >> 16;
    return (unsigned short)r;
}
__device__ __forceinline__ float bf2f(unsigned short u) {
    return __uint_as_float(((unsigned)u) << 16);
}

typedef __attribute__((address_space(1))) const void glb_cv;
typedef __attribute__((address_space(3))) void lds_v;
__device__ __forceinline__ void gload_lds16(const void* g, void* l) {
    __builtin_amdgcn_global_load_lds((glb_cv*)g, (lds_v*)l, 16, 0, 0);
}

// ---------------------------------------------------------------------------
// P1: x [16384][128] fp32 -> xh/xl bf16, transposed to [col][k] per 32-k tile,
// pre-swizzled: idx = tile*4096 + c*32 + ((g^((c>>1)&3))<<3) + (k&7), g=(k>>3)&3
// ---------------------------------------------------------------------------
__global__ void prep_x(const float* __restrict__ x,
                       unsigned short* __restrict__ xh,
                       unsigned short* __restrict__ xl) {
    const int kt = blockIdx.x;   // 0..511
    const int c  = threadIdx.x;  // 0..127
    float v[32];
#pragma unroll
    for (int i = 0; i < 32; ++i)
        v[i] = x[((long)kt * 32 + i) * 128 + c];
    const int f = (c >> 1) & 3;
    unsigned short* oh = xh + (long)kt * 4096 + c * 32;
    unsigned short* ol = xl + (long)kt * 4096 + c * 32;
#pragma unroll
    for (int g = 0; g < 4; ++g) {
        uint4 ph, pl;
        unsigned hp[4], lp[4];
#pragma unroll
        for (int q = 0; q < 4; ++q) {
            float a = v[g * 8 + q * 2], b = v[g * 8 + q * 2 + 1];
            unsigned short ha = f2bf(a), hb = f2bf(b);
            float la = a - bf2f(ha), lb = b - bf2f(hb);
            hp[q] = (unsigned)ha | ((unsigned)hb << 16);
            lp[q] = (unsigned)f2bf(la) | ((unsigned)f2bf(lb) << 16);
        }
        ph.x = hp[0]; ph.y = hp[1]; ph.z = hp[2]; ph.w = hp[3];
        pl.x = lp[0]; pl.y = lp[1]; pl.z = lp[2]; pl.w = lp[3];
        const int gp = g ^ f;
        *(uint4*)&oh[gp * 8] = ph;
        *(uint4*)&ol[gp * 8] = pl;
    }
}

// ---------------------------------------------------------------------------
// G: cpart[ks][i][d] = adj[i, ks-range] @ x[ks-range, d]
// 1024 blocks: ks = b&7 (== XCD id under round-robin -> B slice L2-pinned),
// bmi = b>>3. 256 thr (4 waves). A fetched in 2-iter superchunks:
// thread t covers row (t>>1); chunk cc (0..7) = floats [cc*8+(t&1)*4, +4)
// of the 64-float super-range -> per-instruction 32B/row, 256B/row per super.
// ---------------------------------------------------------------------------
__global__ __launch_bounds__(256, 3) void gemm_adj(
    const float* __restrict__ adj,
    const unsigned short* __restrict__ xh,
    const unsigned short* __restrict__ xl,
    float* __restrict__ cpart) {
    __shared__ __align__(16) unsigned short Ah[BM * BK];
    __shared__ __align__(16) unsigned short Al[BM * BK];
    __shared__ __align__(16) unsigned short Bh[GD * BK];
    __shared__ __align__(16) unsigned short Bl[GD * BK];

    const int t   = threadIdx.x;
    const int b   = blockIdx.x;
    const int ks  = b & 7;
    const int bmi = b >> 3;
    const long rowbase = (long)bmi * BM;
    const int kb0 = ks * KRANGE;
    const int lane = t & 63, wid = t >> 6;
    const int ra = t >> 1;           // A row 0..127 (2 threads/row)
    const int sub = (t & 1) * 4;     // float sub-offset within 8-float group

    f32x16 acc[4];
#pragma unroll
    for (int n = 0; n < 4; ++n)
#pragma unroll
        for (int e = 0; e < 16; ++e) acc[n][e] = 0.0f;

    // float index base of this thread's row in adj, at kb0
    const float* abase = adj + (rowbase + ra) * 16384L + kb0;
    f32x4 pref[8];
#pragma unroll
    for (int cc = 0; cc < 8; ++cc)
        pref[cc] = __builtin_nontemporal_load(
            (const f32x4*)(abase + cc * 8 + sub));

    const int rsw = (ra >> 1) & 3;
    const int rm  = wid * 32 + (lane & 31);   // MFMA row
    const int rswm = (rm >> 1) & 3;

    for (int sup = 0; sup < NSUP; ++sup) {
#pragma unroll
        for (int half = 0; half < 2; ++half) {
            const int it = sup * 2 + half;
            const int kb = kb0 + it * BK;
            __syncthreads();
            // B stage: async global->LDS (pre-swizzled, linear)
            {
                const char* sh = (const char*)(xh + (long)(kb >> 5) * 4096);
                const char* sl = (const char*)(xl + (long)(kb >> 5) * 4096);
#pragma unroll
                for (int j = 0; j < 2; ++j) {
                    const int seg = wid + j * 4;
                    gload_lds16(sh + seg * 1024 + lane * 16, ((char*)Bh) + seg * 1024);
                    gload_lds16(sl + seg * 1024 + lane * 16, ((char*)Bl) + seg * 1024);
                }
            }
            // A stage: convert this half's 4 chunks -> bf16 hi/lo, swizzled
#pragma unroll
            for (int c2 = 0; c2 < 4; ++c2) {
                const f32x4 v = pref[half * 4 + c2];
                unsigned hu[2], lu[2];
#pragma unroll
                for (int q = 0; q < 2; ++q) {
                    unsigned short ha = f2bf(v[2 * q]), hb = f2bf(v[2 * q + 1]);
                    float la = v[2 * q] - bf2f(ha), lb = v[2 * q + 1] - bf2f(hb);
                    hu[q] = (unsigned)ha | ((unsigned)hb << 16);
                    lu[q] = (unsigned)f2bf(la) | ((unsigned)f2bf(lb) << 16);
                }
                const int gp = c2 ^ rsw;
                const int idx = ra * 32 + gp * 8 + sub;
                uint2 H2, L2;
                H2.x = hu[0]; H2.y = hu[1];
                L2.x = lu[0]; L2.y = lu[1];
                *(uint2*)&Ah[idx] = H2;
                *(uint2*)&Al[idx] = L2;
            }
            __syncthreads();   // drains B-loads into LDS + A ds_writes
            // after consuming the last half, prefetch next superchunk;
            // stays in flight over this half's MFMA phase
            if (half == 1 && sup + 1 < NSUP) {
#pragma unroll
                for (int cc = 0; cc < 8; ++cc)
                    pref[cc] = __builtin_nontemporal_load(
                        (const f32x4*)(abase + (sup + 1) * 64 + cc * 8 + sub));
            }
            // MFMA phase
#pragma unroll
            for (int s = 0; s < 2; ++s) {
                const int hh = 2 * s + (lane >> 5);
                bf16x8 am, al2;
                am  = *(const bf16x8*)&Ah[rm * 32 + (hh ^ rswm) * 8];
                al2 = *(const bf16x8*)&Al[rm * 32 + (hh ^ rswm) * 8];
#pragma unroll
                for (int n = 0; n < 4; ++n) {
                    const int c = n * 32 + (lane & 31);
                    const int gp = hh ^ ((c >> 1) & 3);
                    const bf16x8 bn  = *(const bf16x8*)&Bh[c * 32 + gp * 8];
                    const bf16x8 bl4 = *(const bf16x8*)&Bl[c * 32 + gp * 8];
                    acc[n] = __builtin_amdgcn_mfma_f32_32x32x16_bf16(am, bn, acc[n], 0, 0, 0);
                    acc[n] = __builtin_amdgcn_mfma_f32_32x32x16_bf16(am, bl4, acc[n], 0, 0, 0);
                    acc[n] = __builtin_amdgcn_mfma_f32_32x32x16_bf16(al2, bn, acc[n], 0, 0, 0);
                }
            }
        }
    }
    // epilogue: C/D layout row=(e&3)+8*(e>>2)+4*(lane>>5), col=lane&31
    float* cp = cpart + (long)ks * GN * GD;
#pragma unroll
    for (int n = 0; n < 4; ++n) {
        const int c = n * 32 + (lane & 31);
#pragma unroll
        for (int e = 0; e < 16; ++e) {
            const int rl = wid * 32 + (e & 3) + 8 * (e >> 2) + 4 * (lane >> 5);
            __builtin_nontemporal_store(acc[n][e], &cp[(rowbase + rl) * (long)GD + c]);
        }
    }
}

// ---------------------------------------------------------------------------
// T: fused tail. 512 blocks x 256 thr, 32 rows/block. Outer-product matmuls,
// row-major weights straight from L1/L2. LDS: H(16K)+C(16K)+FB(32K)=64K.
// Thread (ogrp=t&31 -> 4 outs, rowgrp=t>>5 -> 4 rows).
// ---------------------------------------------------------------------------
__global__ __launch_bounds__(256, 2) void tail_fused(
    const float* __restrict__ cpart,
    const float* __restrict__ Wq, const float* __restrict__ Wk,
    const float* __restrict__ Wv, const float* __restrict__ Wo,
    const float* __restrict__ ln1s,
    const float* __restrict__ W1, const float* __restrict__ W2,
    const float* __restrict__ ln2s, const float* __restrict__ Wout,
    float* __restrict__ out) {
    __shared__ __align__(16) float H[32][128];
    __shared__ __align__(16) float C[32][128];
    __shared__ __align__(16) float FB[32 * 256];
    float (*B1)[128] = (float (*)[128])FB;

    const int t = threadIdx.x;
    const int ogrp = t & 31, rowgrp = t >> 5;
    const int o4 = ogrp * 4, rbase = rowgrp * 4;
    const long r0 = (long)blockIdx.x * 32;

    // --- step 1: H = sum_ks cpart[ks] ---
#pragma unroll
    for (int j = 0; j < 4; ++j) {
        const int p = t + 256 * j;
        const int row = p >> 5, c4 = (p & 31) * 4;
        f32x4 s = __builtin_nontemporal_load(
            (const f32x4*)&cpart[(r0 + row) * 128 + c4]);
#pragma unroll
        for (int ks = 1; ks < KSPLIT; ++ks) {
            f32x4 v = __builtin_nontemporal_load(
                (const f32x4*)&cpart[((long)ks * GN + r0 + row) * 128 + c4]);
            s += v;
        }
        *(f32x4*)&H[row][c4] = s;
    }
    __syncthreads();

    // --- step 2: q,k ---
    float qa[4][4] = {}, ka[4][4] = {};
    for (int dg = 0; dg < 32; ++dg) {
        f32x4 h4[4];
#pragma unroll
        for (int rr = 0; rr < 4; ++rr) h4[rr] = *(const f32x4*)&H[rbase + rr][dg * 4];
#pragma unroll
        for (int i = 0; i < 4; ++i) {
            const int d = dg * 4 + i;
            const f32x4 wq = *(const f32x4*)&Wq[d * 128 + o4];
            const f32x4 wk = *(const f32x4*)&Wk[d * 128 + o4];
#pragma unroll
            for (int rr = 0; rr < 4; ++rr) {
                const float hv = h4[rr][i];
                qa[rr][0] += hv * wq[0]; qa[rr][1] += hv * wq[1];
                qa[rr][2] += hv * wq[2]; qa[rr][3] += hv * wq[3];
                ka[rr][0] += hv * wk[0]; ka[rr][1] += hv * wk[1];
                ka[rr][2] += hv * wk[2]; ka[rr][3] += hv * wk[3];
            }
        }
    }
    // --- softmax over 8-groups (partner lane = lane^1) ---
    float w[4][4];
#pragma unroll
    for (int rr = 0; rr < 4; ++rr) {
        float s0 = qa[rr][0] * ka[rr][0] * 0.25f;
        float s1 = qa[rr][1] * ka[rr][1] * 0.25f;
        float s2 = qa[rr][2] * ka[rr][2] * 0.25f;
        float s3 = qa[rr][3] * ka[rr][3] * 0.25f;
        float m = fmaxf(fmaxf(s0, s1), fmaxf(s2, s3));
        m = fmaxf(m, __shfl_xor(m, 1, 64));
        float e0 = __expf(s0 - m), e1 = __expf(s1 - m);
        float e2 = __expf(s2 - m), e3 = __expf(s3 - m);
        float sum = e0 + e1 + e2 + e3;
        sum += __shfl_xor(sum, 1, 64);
        float inv = 1.0f / sum;
        w[rr][0] = e0 * inv; w[rr][1] = e1 * inv;
        w[rr][2] = e2 * inv; w[rr][3] = e3 * inv;
    }
    // --- step 3: v, attn -> B1 ---
    {
        float va[4][4] = {};
        for (int dg = 0; dg < 32; ++dg) {
            f32x4 h4[4];
#pragma unroll
            for (int rr = 0; rr < 4; ++rr) h4[rr] = *(const f32x4*)&H[rbase + rr][dg * 4];
#pragma unroll
            for (int i = 0; i < 4; ++i) {
                const int d = dg * 4 + i;
                const f32x4 wv = *(const f32x4*)&Wv[d * 128 + o4];
#pragma unroll
                for (int rr = 0; rr < 4; ++rr) {
                    const float hv = h4[rr][i];
                    va[rr][0] += hv * wv[0]; va[rr][1] += hv * wv[1];
                    va[rr][2] += hv * wv[2]; va[rr][3] += hv * wv[3];
                }
            }
        }
#pragma unroll
        for (int rr = 0; rr < 4; ++rr) {
            f32x4 a;
            a[0] = w[rr][0] * va[rr][0]; a[1] = w[rr][1] * va[rr][1];
            a[2] = w[rr][2] * va[rr][2]; a[3] = w[rr][3] * va[rr][3];
            *(f32x4*)&B1[rbase + rr][o4] = a;
        }
    }
    __syncthreads();
    // --- step 4: Wo + residual + LN1 -> C ---
    {
        float oa[4][4] = {};
        for (int dg = 0; dg < 32; ++dg) {
            f32x4 h4[4];
#pragma unroll
            for (int rr = 0; rr < 4; ++rr) h4[rr] = *(const f32x4*)&B1[rbase + rr][dg * 4];
#pragma unroll
            for (int i = 0; i < 4; ++i) {
                const int d = dg * 4 + i;
                const f32x4 wo = *(const f32x4*)&Wo[d * 128 + o4];
#pragma unroll
                for (int rr = 0; rr < 4; ++rr) {
                    const float hv = h4[rr][i];
                    oa[rr][0] += hv * wo[0]; oa[rr][1] += hv * wo[1];
                    oa[rr][2] += hv * wo[2]; oa[rr][3] += hv * wo[3];
                }
            }
        }
        const f32x4 g1 = *(const f32x4*)&ln1s[o4];
#pragma unroll
        for (int rr = 0; rr < 4; ++rr) {
            const f32x4 hres = *(const f32x4*)&H[rbase + rr][o4];
            float u0 = oa[rr][0] + hres[0], u1 = oa[rr][1] + hres[1];
            float u2 = oa[rr][2] + hres[2], u3 = oa[rr][3] + hres[3];
            float s1 = u0 + u1 + u2 + u3;
            float s2 = u0 * u0 + u1 * u1 + u2 * u2 + u3 * u3;
#pragma unroll
            for (int mk = 1; mk < 32; mk <<= 1) {
                s1 += __shfl_xor(s1, mk, 64);
                s2 += __shfl_xor(s2, mk, 64);
            }
            const float mean = s1 * (1.f / 128.f);
            const float var  = s2 * (1.f / 128.f) - mean * mean;
            const float rstd = rsqrtf(var + 1e-6f);
            f32x4 cvr;
            cvr[0] = (u0 - mean) * rstd * g1[0]; cvr[1] = (u1 - mean) * rstd * g1[1];
            cvr[2] = (u2 - mean) * rstd * g1[2]; cvr[3] = (u3 - mean) * rstd * g1[3];
            *(f32x4*)&C[rbase + rr][o4] = cvr;
        }
    }
    __syncthreads();
    // --- step 5: FB = relu(C @ W1) [32][256] ---
#pragma unroll
    for (int h = 0; h < 2; ++h) {
        float fa[4][4] = {};
        for (int dg = 0; dg < 32; ++dg) {
            f32x4 h4[4];
#pragma unroll
            for (int rr = 0; rr < 4; ++rr) h4[rr] = *(const f32x4*)&C[rbase + rr][dg * 4];
#pragma unroll
            for (int i = 0; i < 4; ++i) {
                const int d = dg * 4 + i;
                const f32x4 w1 = *(const f32x4*)&W1[d * 256 + h * 128 + o4];
#pragma unroll
                for (int rr = 0; rr < 4; ++rr) {
                    const float hv = h4[rr][i];
                    fa[rr][0] += hv * w1[0]; fa[rr][1] += hv * w1[1];
                    fa[rr][2] += hv * w1[2]; fa[rr][3] += hv * w1[3];
                }
            }
        }
#pragma unroll
        for (int rr = 0; rr < 4; ++rr) {
            f32x4 a;
            a[0] = fmaxf(fa[rr][0], 0.f); a[1] = fmaxf(fa[rr][1], 0.f);
            a[2] = fmaxf(fa[rr][2], 0.f); a[3] = fmaxf(fa[rr][3], 0.f);
            *(f32x4*)&FB[(rbase + rr) * 256 + h * 128 + o4] = a;
        }
        __syncthreads();
    }
    // --- step 6: W2 + residual + LN2 -> C (in place) ---
    {
        float ga[4][4] = {};
        for (int dg = 0; dg < 64; ++dg) {
            f32x4 f4[4];
#pragma unroll
            for (int rr = 0; rr < 4; ++rr)
                f4[rr] = *(const f32x4*)&FB[(rbase + rr) * 256 + dg * 4];
#pragma unroll
            for (int i = 0; i < 4; ++i) {
                const int d = dg * 4 + i;
                const f32x4 w2 = *(const f32x4*)&W2[d * 128 + o4];
#pragma unroll
                for (int rr = 0; rr < 4; ++rr) {
                    const float hv = f4[rr][i];
                    ga[rr][0] += hv * w2[0]; ga[rr][1] += hv * w2[1];
                    ga[rr][2] += hv * w2[2]; ga[rr][3] += hv * w2[3];
                }
            }
        }
        const f32x4 g2 = *(const f32x4*)&ln2s[o4];
#pragma unroll
        for (int rr = 0; rr < 4; ++rr) {
            const f32x4 cres = *(const f32x4*)&C[rbase + rr][o4];
            float u0 = ga[rr][0] + cres[0], u1 = ga[rr][1] + cres[1];
            float u2 = ga[rr][2] + cres[2], u3 = ga[rr][3] + cres[3];
            float s1 = u0 + u1 + u2 + u3;
            float s2 = u0 * u0 + u1 * u1 + u2 * u2 + u3 * u3;
#pragma unroll
            for (int mk = 1; mk < 32; mk <<= 1) {
                s1 += __shfl_xor(s1, mk, 64);
                s2 += __shfl_xor(s2, mk, 64);
            }
            const float mean = s1 * (1.f / 128.f);
            const float var  = s2 * (1.f / 128.f) - mean * mean;
            const float rstd = rsqrtf(var + 1e-6f);
            f32x4 cvr;
            cvr[0] = (u0 - mean) * rstd * g2[0]; cvr[1] = (u1 - mean) * rstd * g2[1];
            cvr[2] = (u2 - mean) * rstd * g2[2]; cvr[3] = (u3 - mean) * rstd * g2[3];
            *(f32x4*)&C[rbase + rr][o4] = cvr;
        }
    }
    __syncthreads();
    // --- step 7: out = C @ Wout [32][40] ---
    {
        const int r7 = t >> 3, ob = t & 7;
        float acc[5] = {0.f, 0.f, 0.f, 0.f, 0.f};
        for (int dg = 0; dg < 32; ++dg) {
            const f32x4 c4 = *(const f32x4*)&C[r7][dg * 4];
#pragma unroll
            for (int i = 0; i < 4; ++i) {
                const int d = dg * 4 + i;
                const float hv = c4[i];
#pragma unroll
                for (int jj = 0; jj < 5; ++jj)
                    acc[jj] += hv * Wout[d * 40 + ob + 8 * jj];
            }
        }
#pragma unroll
        for (int jj = 0; jj < 5; ++jj)
            out[(r0 + r7) * 40 + ob + 8 * jj] = acc[jj];
    }
}

// ---------------------------------------------------------------------------
extern "C" void kernel_launch(void* const* d_in, const int* in_sizes, int n_in,
                              void* d_out, int out_size, void* d_ws, size_t ws_size,
                              hipStream_t stream) {
    const float* x    = (const float*)d_in[0];
    const float* adj  = (const float*)d_in[1];
    const float* Wq   = (const float*)d_in[2];
    const float* Wk   = (const float*)d_in[3];
    const float* Wv   = (const float*)d_in[4];
    const float* Wo   = (const float*)d_in[5];
    const float* ln1s = (const float*)d_in[6];
    const float* W1   = (const float*)d_in[7];
    const float* W2   = (const float*)d_in[8];
    const float* ln2s = (const float*)d_in[9];
    const float* Wout = (const float*)d_in[10];

    char* ws = (char*)d_ws;
    unsigned short* xh = (unsigned short*)(ws);                  // 4 MB
    unsigned short* xl = (unsigned short*)(ws + (4L << 20));     // 4 MB
    float* cpart       = (float*)(ws + (8L << 20));              // 64 MB

    prep_x<<<512, 128, 0, stream>>>(x, xh, xl);
    gemm_adj<<<1024, 256, 0, stream>>>(adj, xh, xl, cpart);
    tail_fused<<<512, 256, 0, stream>>>(cpart, Wq, Wk, Wv, Wo, ln1s,
                                        W1, W2, ln2s, Wout, (float*)d_out);
}